// Round 6
// baseline (259.533 us; speedup 1.0000x reference)
//
#include <hip/hip_runtime.h>

// ---------------------------------------------------------------------------
// MultiHeadSelfAttention: B=4 S=2048 D=1024 H=16 DK=64, RoPE, causal, out-proj
// Round 6: attn grid un-paired (1024 blocks, heavy-first qt=15-px) to restore
//          occupancy; T13 defer-max (skip rescale when max growth <= 11.5 in
//          exp2 domain). Rest unchanged from round 5.
// ---------------------------------------------------------------------------

typedef _Float16 f16;
typedef _Float16 f16x4 __attribute__((ext_vector_type(4)));
typedef _Float16 f16x8 __attribute__((ext_vector_type(8)));
typedef float    f32x4 __attribute__((ext_vector_type(4)));
typedef __fp16   h16x2 __attribute__((ext_vector_type(2)));

typedef __attribute__((address_space(1))) void gvoid_t;
typedef __attribute__((address_space(3))) void lvoid_t;

// async global->LDS, 16B per lane; LDS dest = wave-uniform base + lane*16
#define GLD16(g, l) __builtin_amdgcn_global_load_lds( \
    (gvoid_t*)(const void*)(g), (lvoid_t*)(l), 16, 0, 0)

constexpr int BB = 4, SS = 2048, DD = 1024, HH = 16, DKK = 64;
constexpr int MM = BB * SS;  // 8192

// ---------------- f32 -> f16 convert (vectorized) ----------------
__global__ void cvt_kernel(const float4* __restrict__ in, f16x4* __restrict__ out, int n4) {
    int stride = gridDim.x * blockDim.x;
    for (int i = blockIdx.x * blockDim.x + threadIdx.x; i < n4; i += stride) {
        float4 v = in[i];
        f16x4 o;
        o[0] = (f16)v.x; o[1] = (f16)v.y; o[2] = (f16)v.z; o[3] = (f16)v.w;
        out[i] = o;
    }
}

// 4 weight matrices in one launch; dst regions are contiguous in ws
__global__ void cvt4_kernel(const float4* __restrict__ a, const float4* __restrict__ b,
                            const float4* __restrict__ c, const float4* __restrict__ d,
                            f16x4* __restrict__ out, int n4per) {
    const float4* srcs[4] = {a, b, c, d};
    const float4* src = srcs[blockIdx.y];
    f16x4* dst = out + (size_t)blockIdx.y * n4per;
    int stride = gridDim.x * blockDim.x;
    for (int i = blockIdx.x * blockDim.x + threadIdx.x; i < n4per; i += stride) {
        float4 v = src[i];
        f16x4 o;
        o[0] = (f16)v.x; o[1] = (f16)v.y; o[2] = (f16)v.z; o[3] = (f16)v.w;
        dst[i] = o;
    }
}

// ---------------- RoPE tables: ctab/stab[s][dk] = cos/sin(s * invfreq[dk>>1])
__global__ void rope_tab_kernel(float* __restrict__ ctab, float* __restrict__ stab) {
    int idx = blockIdx.x * blockDim.x + threadIdx.x;
    if (idx >= SS * DKK) return;
    int s = idx >> 6, dk = idx & 63, i = dk >> 1;
    float inv = powf(10000.0f, -(float)(2 * i) / (float)DKK);
    float ang = (float)s * inv;
    ctab[idx] = cosf(ang);
    stab[idx] = sinf(ang);
}

// ---------------- GEMM core: C[128x128] tile, A[M][K], B-as-[N][K], K=1024 ---
// BK=64, double-buffered LDS, global_load_lds staging with XOR-swizzled source,
// ONE barrier per K-step, 16x16x32 f16 MFMA, 4 waves 2x2.
__device__ __forceinline__ void gemm_core(
    const f16* __restrict__ A, const f16* __restrict__ Bm,
    f16* As, f16* Bs, f32x4 (&acc)[4][4], int bm, int bn)
{
    const int tid  = threadIdx.x;
    const int lane = tid & 63, wid = tid >> 6;
    const int lrow = lane & 15, lk = lane >> 4;
    const int wm = (wid >> 1) * 64, wn = (wid & 1) * 64;

    const int r_ = tid >> 3, c_ = tid & 7;

    auto STAGE = [&](int buf, int k0) {
#pragma unroll
        for (int j = 0; j < 4; ++j) {
            int r = j * 32 + r_;
            int cs = (c_ ^ (r & 7)) * 8;
            GLD16(A  + (size_t)(bm + r) * 1024 + k0 + cs, As + buf * 8192 + (j * 256 + wid * 64) * 8);
            GLD16(Bm + (size_t)(bn + r) * 1024 + k0 + cs, Bs + buf * 8192 + (j * 256 + wid * 64) * 8);
        }
    };

    auto COMPUTE = [&](int buf) {
        const f16* Ab = As + buf * 8192;
        const f16* Bb = Bs + buf * 8192;
#pragma unroll
        for (int kk = 0; kk < 2; ++kk) {
            f16x8 af[4], bf[4];
#pragma unroll
            for (int mi = 0; mi < 4; ++mi) {
                int row = wm + mi * 16 + lrow;
                af[mi] = *(const f16x8*)&Ab[row * 64 + ((kk * 4 + lk) ^ (row & 7)) * 8];
            }
#pragma unroll
            for (int ni = 0; ni < 4; ++ni) {
                int row = wn + ni * 16 + lrow;
                bf[ni] = *(const f16x8*)&Bb[row * 64 + ((kk * 4 + lk) ^ (row & 7)) * 8];
            }
#pragma unroll
            for (int mi = 0; mi < 4; ++mi)
#pragma unroll
                for (int ni = 0; ni < 4; ++ni)
                    acc[mi][ni] = __builtin_amdgcn_mfma_f32_16x16x32_f16(
                        af[mi], bf[ni], acc[mi][ni], 0, 0, 0);
        }
    };

    STAGE(0, 0);
    __syncthreads();
    int cur = 0;
#pragma unroll 1
    for (int t = 0; t < 15; ++t) {
        STAGE(cur ^ 1, (t + 1) * 64);   // issue next tile FIRST (hides under MFMA)
        COMPUTE(cur);
        __syncthreads();                // drains vmcnt(0): next buffer ready
        cur ^= 1;
    }
    COMPUTE(cur);                       // tail, no prefetch
}

// ---------------- QKV GEMM + RoPE epilogue; z: 0=Q 1=K 2=V ----------------
__global__ __launch_bounds__(256) void qkv_gemm(
    const f16* __restrict__ xb,
    const f16* __restrict__ wqb, const f16* __restrict__ wkb, const f16* __restrict__ wvb,
    f16* __restrict__ Qr, f16* __restrict__ Kr, f16* __restrict__ Vt,
    const float* __restrict__ ctab, const float* __restrict__ stab)
{
    __shared__ __align__(16) f16 As[2 * 128 * 64];
    __shared__ __align__(16) f16 Bs[2 * 128 * 64];
    const int z = blockIdx.z;
    const f16* Bm = (z == 0) ? wqb : (z == 1) ? wkb : wvb;
    const int bm = blockIdx.y * 128, bn = blockIdx.x * 128;
    f32x4 acc[4][4] = {};
    gemm_core(xb, Bm, As, Bs, acc, bm, bn);

    const int tid = threadIdx.x, lane = tid & 63, wid = tid >> 6;
    const int lrow = lane & 15, lk = lane >> 4;
    const int wm = (wid >> 1) * 64, wn = (wid & 1) * 64;

    if (z == 2) {
        // V stored transposed: [b,h,dk,s] so attention stages Vt rows directly
#pragma unroll
        for (int mi = 0; mi < 4; ++mi)
#pragma unroll
            for (int ni = 0; ni < 4; ++ni)
#pragma unroll
                for (int r = 0; r < 4; ++r) {
                    int row = bm + wm + mi * 16 + lk * 4 + r;   // (b,s)
                    int col = bn + wn + ni * 16 + lrow;          // (h,dk)
                    int b = row >> 11, s = row & 2047, h = col >> 6, dk = col & 63;
                    Vt[((size_t)(b * HH + h) * DKK + dk) * SS + s] = (f16)acc[mi][ni][r];
                }
    } else {
        f16* Out = (z == 0) ? Qr : Kr;
        // fold 1/sqrt(DK) AND log2e (attn works in exp2 domain) into Q
        const float scale = (z == 0) ? 0.125f * 1.44269504088896f : 1.0f;
#pragma unroll
        for (int mi = 0; mi < 4; ++mi)
#pragma unroll
            for (int ni = 0; ni < 4; ++ni)
#pragma unroll
                for (int r = 0; r < 4; ++r) {
                    int row = bm + wm + mi * 16 + lk * 4 + r;
                    int col = bn + wn + ni * 16 + lrow;
                    int b = row >> 11, s = row & 2047, h = col >> 6, dk = col & 63;
                    float v = acc[mi][ni][r];
                    float partner = __shfl_xor(v, 1);   // adjacent column (same rows)
                    float cc = ctab[s * DKK + dk], ssn = stab[s * DKK + dk];
                    float rot = (col & 1) ? partner : -partner;
                    float o = (v * cc + rot * ssn) * scale;
                    Out[((size_t)(b * HH + h) * SS + s) * DKK + dk] = (f16)o;
                }
    }
}

// ---------------- Flash attention ----------------
// One q-tile of 128 rows per block; 16 q-tiles x 64 bh = 1024 blocks,
// heavy-first (qt = 15 - px) so in-order dispatch packs well.
// 4 waves; each wave owns 32 q-rows (mi=0,1). Swapped QK^T (mfma(K,Q)) ->
// softmax reduction lane-local + shfl_xor(16,32). exp2-domain softmax with
// T13 defer-max (threshold 11.5 ~ e^8). P packed via cvt_pkrtz ->
// ds_write_b64; PV = mfma(V,P) accumulating O^T[dk][q].
__global__ __launch_bounds__(256, 3) void attn_kernel(
    const f16* __restrict__ Q, const f16* __restrict__ K, const f16* __restrict__ Vt,
    f16* __restrict__ attnB)
{
    __shared__ __align__(16) f16 Ks[2][64 * 64];   // [kv][dk], swizzled chunks
    __shared__ __align__(16) f16 Vs[2][64 * 64];   // [dk][kv], swizzled chunks
    __shared__ __align__(16) f16 Ps[4][32 * 64];   // per-wave P[q_local][kv], swizzled

    const int tid = threadIdx.x, lane = tid & 63, wid = tid >> 6;
    const int lrow = lane & 15, lk = lane >> 4;
    const int bh = blockIdx.y;               // b*16+h
    const int b = bh >> 4, h = bh & 15;

    const f16* Qb = Q  + (size_t)bh * SS * DKK;
    const f16* Kb = K  + (size_t)bh * SS * DKK;
    const f16* Vb = Vt + (size_t)bh * DKK * SS;
    f16* PsW = &Ps[wid][0];

    const int qt = 15 - (int)blockIdx.x;     // heavy-first
    const int qw = qt * 128 + wid * 32;      // this wave's 32 q-rows
    const int nt = 2 * qt + 2;               // causal KV tiles of 64

    // Q fragments in registers: qf[mi][kk] = Q[qw+mi*16+lrow][kk*32+lk*8..]
    f16x8 qf[2][2];
#pragma unroll
    for (int mi = 0; mi < 2; ++mi)
#pragma unroll
        for (int kk = 0; kk < 2; ++kk)
            qf[mi][kk] = *(const f16x8*)&Qb[(size_t)(qw + mi * 16 + lrow) * DKK + kk * 32 + lk * 8];

    f32x4 oacc[2][4] = {};
    float mst[2] = {-1e30f, -1e30f}, lst[2] = {0.0f, 0.0f};
    int cur = 0;

    // prologue stage tile 0
#pragma unroll
    for (int j = 0; j < 2; ++j) {
        int ci = j * 256 + tid;
        int r = ci >> 3, c = ci & 7;
        int cs = (c ^ (r & 7)) * 8;
        GLD16(Kb + (size_t)r * DKK + cs, &Ks[cur][(j * 256 + wid * 64) * 8]);
        GLD16(Vb + (size_t)r * SS  + cs, &Vs[cur][(j * 256 + wid * 64) * 8]);
    }
    __syncthreads();

    for (int t = 0; t < nt; ++t) {
        const int kv0 = t * 64;
        // prefetch next KV tile into other buffer
        if (t + 1 < nt) {
            const int kvn = kv0 + 64;
#pragma unroll
            for (int j = 0; j < 2; ++j) {
                int ci = j * 256 + tid;
                int r = ci >> 3, c = ci & 7;
                int cs = (c ^ (r & 7)) * 8;
                GLD16(Kb + (size_t)(kvn + r) * DKK + cs, &Ks[cur ^ 1][(j * 256 + wid * 64) * 8]);
                GLD16(Vb + (size_t)r * SS + kvn + cs,    &Vs[cur ^ 1][(j * 256 + wid * 64) * 8]);
            }
        }

        if (kv0 <= qw + 31) {   // wave has at least one unmasked column
            // ---- swapped QK^T: sacc[mi][ni] = S^T chunks ----
            f32x4 sacc[2][4] = {};
#pragma unroll
            for (int kk = 0; kk < 2; ++kk)
#pragma unroll
                for (int ni = 0; ni < 4; ++ni) {
                    int row = ni * 16 + lrow;
                    f16x8 kf = *(const f16x8*)&Ks[cur][row * 64 + ((kk * 4 + lk) ^ (row & 7)) * 8];
#pragma unroll
                    for (int mi = 0; mi < 2; ++mi)
                        sacc[mi][ni] = __builtin_amdgcn_mfma_f32_16x16x32_f16(
                            kf, qf[mi][kk], sacc[mi][ni], 0, 0, 0);
                }

            // ---- softmax: lane owns q = qw + mi*16 + lrow ----
#pragma unroll
            for (int mi = 0; mi < 2; ++mi) {
                const int q  = qw + mi * 16 + lrow;
                const int ql = mi * 16 + lrow;
                if (kv0 + 63 > q) {          // causal mask (diag tiles only)
#pragma unroll
                    for (int ni = 0; ni < 4; ++ni)
#pragma unroll
                        for (int r = 0; r < 4; ++r)
                            if (kv0 + ni * 16 + lk * 4 + r > q) sacc[mi][ni][r] = -1e30f;
                }
                float m0 = -1e30f;
#pragma unroll
                for (int ni = 0; ni < 4; ++ni) {
                    float a = fmaxf(sacc[mi][ni][0], sacc[mi][ni][1]);
                    float bx = fmaxf(sacc[mi][ni][2], sacc[mi][ni][3]);
                    m0 = fmaxf(m0, fmaxf(a, bx));
                }
                m0 = fmaxf(m0, __shfl_xor(m0, 16));
                m0 = fmaxf(m0, __shfl_xor(m0, 32));
                // T13 defer-max: only rescale when the max really grew
                if (!__all(m0 - mst[mi] <= 11.5f)) {
                    const float mnew  = fmaxf(mst[mi], m0);
                    const float alpha = exp2f(mst[mi] - mnew);
                    mst[mi] = mnew;
                    lst[mi] *= alpha;
#pragma unroll
                    for (int no = 0; no < 4; ++no)
#pragma unroll
                        for (int r = 0; r < 4; ++r)
                            oacc[mi][no][r] *= alpha;
                }
                const float mref = mst[mi];
                float rsum = 0.0f;
#pragma unroll
                for (int ni = 0; ni < 4; ++ni) {
                    float p0 = exp2f(sacc[mi][ni][0] - mref);
                    float p1 = exp2f(sacc[mi][ni][1] - mref);
                    float p2 = exp2f(sacc[mi][ni][2] - mref);
                    float p3 = exp2f(sacc[mi][ni][3] - mref);
                    rsum += (p0 + p1) + (p2 + p3);
                    h16x2 w0 = __builtin_amdgcn_cvt_pkrtz(p0, p1);
                    h16x2 w1 = __builtin_amdgcn_cvt_pkrtz(p2, p3);
                    f16x4 w;
                    w[0] = (f16)w0[0]; w[1] = (f16)w0[1];
                    w[2] = (f16)w1[0]; w[3] = (f16)w1[1];
                    const int c = ni * 2 + (lk >> 1);
                    *(f16x4*)&PsW[ql * 64 + ((c ^ (ql & 7)) * 8) + (lk & 1) * 4] = w;
                }
                rsum += __shfl_xor(rsum, 16);
                rsum += __shfl_xor(rsum, 32);
                lst[mi] += rsum;
            }

            // ---- PV: O^T[dk][q] += V^T[dk][kv] x P[q][kv] ----
#pragma unroll
            for (int kk = 0; kk < 2; ++kk) {
                f16x8 pa[2];
#pragma unroll
                for (int mi = 0; mi < 2; ++mi) {
                    const int ql = mi * 16 + lrow;
                    pa[mi] = *(const f16x8*)&PsW[ql * 64 + ((kk * 4 + lk) ^ (ql & 7)) * 8];
                }
#pragma unroll
                for (int no = 0; no < 4; ++no) {
                    int row = no * 16 + lrow;
                    f16x8 vf = *(const f16x8*)&Vs[cur][row * 64 + ((kk * 4 + lk) ^ (row & 7)) * 8];
#pragma unroll
                    for (int mi = 0; mi < 2; ++mi)
                        oacc[mi][no] = __builtin_amdgcn_mfma_f32_16x16x32_f16(
                            vf, pa[mi], oacc[mi][no], 0, 0, 0);
                }
            }
        }

        __syncthreads();   // prefetch complete + everyone done reading cur
        cur ^= 1;
    }

    // normalize + store attn[b,s,h,dk] (f16); oacc[mi][no][r] = O[dk][q]
#pragma unroll
    for (int mi = 0; mi < 2; ++mi) {
        const float rl = 1.0f / lst[mi];
        const int q = qw + mi * 16 + lrow;
#pragma unroll
        for (int no = 0; no < 4; ++no) {
            f16x4 w;
#pragma unroll
            for (int r = 0; r < 4; ++r) w[r] = (f16)(oacc[mi][no][r] * rl);
            *(f16x4*)&attnB[((size_t)(b * SS) + q) * DD + h * DKK + no * 16 + lk * 4] = w;
        }
    }
}

// ---------------- Out projection GEMM (f32 output) ----------------
__global__ __launch_bounds__(256) void out_gemm(
    const f16* __restrict__ attnB, const f16* __restrict__ wob, float* __restrict__ out)
{
    __shared__ __align__(16) f16 As[2 * 128 * 64];
    __shared__ __align__(16) f16 Bs[2 * 128 * 64];
    const int bm = blockIdx.y * 128, bn = blockIdx.x * 128;
    f32x4 acc[4][4] = {};
    gemm_core(attnB, wob, As, Bs, acc, bm, bn);
    const int tid = threadIdx.x, lane = tid & 63, wid = tid >> 6;
    const int lrow = lane & 15, lk = lane >> 4;
    const int wm = (wid >> 1) * 64, wn = (wid & 1) * 64;
#pragma unroll
    for (int mi = 0; mi < 4; ++mi)
#pragma unroll
        for (int ni = 0; ni < 4; ++ni)
#pragma unroll
            for (int r = 0; r < 4; ++r) {
                int row = bm + wm + mi * 16 + lk * 4 + r;
                int col = bn + wn + ni * 16 + lrow;
                out[(size_t)row * 1024 + col] = acc[mi][ni][r];
            }
}

// ---------------------------------------------------------------------------
extern "C" void kernel_launch(void* const* d_in, const int* in_sizes, int n_in,
                              void* d_out, int out_size, void* d_ws, size_t ws_size,
                              hipStream_t stream) {
    const float* x  = (const float*)d_in[0];
    const float* wq = (const float*)d_in[1];
    const float* wk = (const float*)d_in[2];
    const float* wv = (const float*)d_in[3];
    const float* wo = (const float*)d_in[4];
    float* out = (float*)d_out;

    // workspace layout (f16 elements); attnB aliases xb (xb dead after QKV gemm)
    constexpr size_t NXB = (size_t)MM * DD;   // 8388608
    constexpr size_t NW  = (size_t)DD * DD;   // 1048576
    f16* xb  = (f16*)d_ws;
    f16* wqb = xb  + NXB;
    f16* wkb = wqb + NW;
    f16* wvb = wkb + NW;
    f16* wob = wvb + NW;
    f16* Qr  = wob + NW;
    f16* Kr  = Qr  + NXB;
    f16* Vt  = Kr  + NXB;
    float* ctab = (float*)(Vt + NXB);
    float* stab = ctab + SS * DKK;
    f16* attnB = xb;

    cvt_kernel<<<2048, 256, 0, stream>>>((const float4*)x, (f16x4*)xb, (int)(NXB / 4));
    cvt4_kernel<<<dim3(512, 4), 256, 0, stream>>>((const float4*)wq, (const float4*)wk,
                                                  (const float4*)wv, (const float4*)wo,
                                                  (f16x4*)wqb, (int)(NW / 4));
    rope_tab_kernel<<<(SS * DKK + 255) / 256, 256, 0, stream>>>(ctab, stab);

    qkv_gemm<<<dim3(8, 64, 3), 256, 0, stream>>>(xb, wqb, wkb, wvb, Qr, Kr, Vt, ctab, stab);
    attn_kernel<<<dim3(16, 64), 256, 0, stream>>>(Qr, Kr, Vt, attnB);
    out_gemm<<<dim3(8, 64), 256, 0, stream>>>(attnB, wob, out);
}

// Round 7
// 190.610 us; speedup vs baseline: 1.3616x; 1.3616x over previous
//
#include <hip/hip_runtime.h>

// ---------------------------------------------------------------------------
// MultiHeadSelfAttention: B=4 S=2048 D=1024 H=16 DK=64, RoPE, causal, out-proj
// Round 7: T4 counted-vmcnt pipeline (never drain vmcnt(0) in steady state)
//   in BOTH gemm_core and attn; raw s_barrier pairs instead of __syncthreads.
//   Attn grid: truly-global heavy-first (qt = 15 - bx/64).
// ---------------------------------------------------------------------------

typedef _Float16 f16;
typedef _Float16 f16x4 __attribute__((ext_vector_type(4)));
typedef _Float16 f16x8 __attribute__((ext_vector_type(8)));
typedef float    f32x4 __attribute__((ext_vector_type(4)));
typedef __fp16   h16x2 __attribute__((ext_vector_type(2)));

typedef __attribute__((address_space(1))) void gvoid_t;
typedef __attribute__((address_space(3))) void lvoid_t;

// async global->LDS, 16B per lane; LDS dest = wave-uniform base + lane*16
#define GLD16(g, l) __builtin_amdgcn_global_load_lds( \
    (gvoid_t*)(const void*)(g), (lvoid_t*)(l), 16, 0, 0)

// counted vmem wait: allow N instructions to remain in flight
#define VMCNT(n) asm volatile("s_waitcnt vmcnt(" #n ")" ::: "memory")

// raw workgroup barrier with scheduler fences (no vmcnt drain!)
__device__ __forceinline__ void bar() {
    __builtin_amdgcn_sched_barrier(0);
    __builtin_amdgcn_s_barrier();
    __builtin_amdgcn_sched_barrier(0);
}

constexpr int BB = 4, SS = 2048, DD = 1024, HH = 16, DKK = 64;
constexpr int MM = BB * SS;  // 8192

// ---------------- f32 -> f16 convert (vectorized) ----------------
__global__ void cvt_kernel(const float4* __restrict__ in, f16x4* __restrict__ out, int n4) {
    int stride = gridDim.x * blockDim.x;
    for (int i = blockIdx.x * blockDim.x + threadIdx.x; i < n4; i += stride) {
        float4 v = in[i];
        f16x4 o;
        o[0] = (f16)v.x; o[1] = (f16)v.y; o[2] = (f16)v.z; o[3] = (f16)v.w;
        out[i] = o;
    }
}

// 4 weight matrices in one launch; dst regions are contiguous in ws
__global__ void cvt4_kernel(const float4* __restrict__ a, const float4* __restrict__ b,
                            const float4* __restrict__ c, const float4* __restrict__ d,
                            f16x4* __restrict__ out, int n4per) {
    const float4* srcs[4] = {a, b, c, d};
    const float4* src = srcs[blockIdx.y];
    f16x4* dst = out + (size_t)blockIdx.y * n4per;
    int stride = gridDim.x * blockDim.x;
    for (int i = blockIdx.x * blockDim.x + threadIdx.x; i < n4per; i += stride) {
        float4 v = src[i];
        f16x4 o;
        o[0] = (f16)v.x; o[1] = (f16)v.y; o[2] = (f16)v.z; o[3] = (f16)v.w;
        dst[i] = o;
    }
}

// ---------------- RoPE tables: ctab/stab[s][dk] = cos/sin(s * invfreq[dk>>1])
__global__ void rope_tab_kernel(float* __restrict__ ctab, float* __restrict__ stab) {
    int idx = blockIdx.x * blockDim.x + threadIdx.x;
    if (idx >= SS * DKK) return;
    int s = idx >> 6, dk = idx & 63, i = dk >> 1;
    float inv = powf(10000.0f, -(float)(2 * i) / (float)DKK);
    float ang = (float)s * inv;
    ctab[idx] = cosf(ang);
    stab[idx] = sinf(ang);
}

// ---------------- GEMM core: C[128x128] tile, A[M][K], B-as-[N][K], K=1024 ---
// BK=64, double-buffered LDS, global_load_lds staging with XOR-swizzled source,
// counted vmcnt(8) pipeline: tile t+1's 8 loads/thread stay in flight across
// both barriers and the whole compute of tile t.
__device__ __forceinline__ void gemm_core(
    const f16* __restrict__ A, const f16* __restrict__ Bm,
    f16* As, f16* Bs, f32x4 (&acc)[4][4], int bm, int bn)
{
    const int tid  = threadIdx.x;
    const int lane = tid & 63, wid = tid >> 6;
    const int lrow = lane & 15, lk = lane >> 4;
    const int wm = (wid >> 1) * 64, wn = (wid & 1) * 64;

    const int r_ = tid >> 3, c_ = tid & 7;

    auto STAGE = [&](int buf, int k0) {
#pragma unroll
        for (int j = 0; j < 4; ++j) {
            int r = j * 32 + r_;
            int cs = (c_ ^ (r & 7)) * 8;
            GLD16(A  + (size_t)(bm + r) * 1024 + k0 + cs, As + buf * 8192 + (j * 256 + wid * 64) * 8);
            GLD16(Bm + (size_t)(bn + r) * 1024 + k0 + cs, Bs + buf * 8192 + (j * 256 + wid * 64) * 8);
        }
    };

    auto COMPUTE = [&](int buf) {
        const f16* Ab = As + buf * 8192;
        const f16* Bb = Bs + buf * 8192;
#pragma unroll
        for (int kk = 0; kk < 2; ++kk) {
            f16x8 af[4], bf[4];
#pragma unroll
            for (int mi = 0; mi < 4; ++mi) {
                int row = wm + mi * 16 + lrow;
                af[mi] = *(const f16x8*)&Ab[row * 64 + ((kk * 4 + lk) ^ (row & 7)) * 8];
            }
#pragma unroll
            for (int ni = 0; ni < 4; ++ni) {
                int row = wn + ni * 16 + lrow;
                bf[ni] = *(const f16x8*)&Bb[row * 64 + ((kk * 4 + lk) ^ (row & 7)) * 8];
            }
#pragma unroll
            for (int mi = 0; mi < 4; ++mi)
#pragma unroll
                for (int ni = 0; ni < 4; ++ni)
                    acc[mi][ni] = __builtin_amdgcn_mfma_f32_16x16x32_f16(
                        af[mi], bf[ni], acc[mi][ni], 0, 0, 0);
        }
    };

    STAGE(0, 0);           // tile 0 in flight (8 ops/thread)
    int cur = 0;
#pragma unroll 1
    for (int t = 0; t < 16; ++t) {
        if (t < 15) { STAGE(cur ^ 1, (t + 1) * 64); VMCNT(8); }  // wait tile t only
        else        { VMCNT(0); }                                 // last: drain
        bar();             // all waves see buf[cur] complete
        COMPUTE(cur);
        bar();             // everyone done reading buf[cur] before it's re-staged
        cur ^= 1;
    }
}

// ---------------- QKV GEMM + RoPE epilogue; z: 0=Q 1=K 2=V ----------------
__global__ __launch_bounds__(256) void qkv_gemm(
    const f16* __restrict__ xb,
    const f16* __restrict__ wqb, const f16* __restrict__ wkb, const f16* __restrict__ wvb,
    f16* __restrict__ Qr, f16* __restrict__ Kr, f16* __restrict__ Vt,
    const float* __restrict__ ctab, const float* __restrict__ stab)
{
    __shared__ __align__(16) f16 As[2 * 128 * 64];
    __shared__ __align__(16) f16 Bs[2 * 128 * 64];
    const int z = blockIdx.z;
    const f16* Bm = (z == 0) ? wqb : (z == 1) ? wkb : wvb;
    const int bm = blockIdx.y * 128, bn = blockIdx.x * 128;
    f32x4 acc[4][4] = {};
    gemm_core(xb, Bm, As, Bs, acc, bm, bn);

    const int tid = threadIdx.x, lane = tid & 63, wid = tid >> 6;
    const int lrow = lane & 15, lk = lane >> 4;
    const int wm = (wid >> 1) * 64, wn = (wid & 1) * 64;

    if (z == 2) {
        // V stored transposed: [b,h,dk,s] so attention stages Vt rows directly
#pragma unroll
        for (int mi = 0; mi < 4; ++mi)
#pragma unroll
            for (int ni = 0; ni < 4; ++ni)
#pragma unroll
                for (int r = 0; r < 4; ++r) {
                    int row = bm + wm + mi * 16 + lk * 4 + r;   // (b,s)
                    int col = bn + wn + ni * 16 + lrow;          // (h,dk)
                    int b = row >> 11, s = row & 2047, h = col >> 6, dk = col & 63;
                    Vt[((size_t)(b * HH + h) * DKK + dk) * SS + s] = (f16)acc[mi][ni][r];
                }
    } else {
        f16* Out = (z == 0) ? Qr : Kr;
        // fold 1/sqrt(DK) AND log2e (attn works in exp2 domain) into Q
        const float scale = (z == 0) ? 0.125f * 1.44269504088896f : 1.0f;
#pragma unroll
        for (int mi = 0; mi < 4; ++mi)
#pragma unroll
            for (int ni = 0; ni < 4; ++ni)
#pragma unroll
                for (int r = 0; r < 4; ++r) {
                    int row = bm + wm + mi * 16 + lk * 4 + r;
                    int col = bn + wn + ni * 16 + lrow;
                    int b = row >> 11, s = row & 2047, h = col >> 6, dk = col & 63;
                    float v = acc[mi][ni][r];
                    float partner = __shfl_xor(v, 1);   // adjacent column (same rows)
                    float cc = ctab[s * DKK + dk], ssn = stab[s * DKK + dk];
                    float rot = (col & 1) ? partner : -partner;
                    float o = (v * cc + rot * ssn) * scale;
                    Out[((size_t)(b * HH + h) * SS + s) * DKK + dk] = (f16)o;
                }
    }
}

// ---------------- Flash attention ----------------
// One q-tile of 128 rows per block; 1024 blocks, GLOBAL heavy-first
// (qt = 15 - bx/64, bh = bx%64): the 64 heaviest (32-tile) blocks dispatch
// first, light ones backfill. 4 waves; wave owns 32 q-rows. Swapped QK^T,
// lane-local softmax + shfl_xor(16,32), exp2 domain, T13 defer-max.
// Counted vmcnt(4) pipeline: next KV tile's 4 loads/thread stay in flight
// across both barriers and the whole compute.
__global__ __launch_bounds__(256, 3) void attn_kernel(
    const f16* __restrict__ Q, const f16* __restrict__ K, const f16* __restrict__ Vt,
    f16* __restrict__ attnB)
{
    __shared__ __align__(16) f16 Ks[2][64 * 64];   // [kv][dk], swizzled chunks
    __shared__ __align__(16) f16 Vs[2][64 * 64];   // [dk][kv], swizzled chunks
    __shared__ __align__(16) f16 Ps[4][32 * 64];   // per-wave P[q_local][kv], swizzled

    const int tid = threadIdx.x, lane = tid & 63, wid = tid >> 6;
    const int lrow = lane & 15, lk = lane >> 4;
    const int bx = blockIdx.x;
    const int qt = 15 - (bx >> 6);           // global heavy-first
    const int bh = bx & 63;                  // b*16+h
    const int b = bh >> 4, h = bh & 15;

    const f16* Qb = Q  + (size_t)bh * SS * DKK;
    const f16* Kb = K  + (size_t)bh * SS * DKK;
    const f16* Vb = Vt + (size_t)bh * DKK * SS;
    f16* PsW = &Ps[wid][0];

    const int qw = qt * 128 + wid * 32;      // this wave's 32 q-rows
    const int nt = 2 * qt + 2;               // causal KV tiles of 64

    // Q fragments in registers: qf[mi][kk] = Q[qw+mi*16+lrow][kk*32+lk*8..]
    f16x8 qf[2][2];
#pragma unroll
    for (int mi = 0; mi < 2; ++mi)
#pragma unroll
        for (int kk = 0; kk < 2; ++kk)
            qf[mi][kk] = *(const f16x8*)&Qb[(size_t)(qw + mi * 16 + lrow) * DKK + kk * 32 + lk * 8];

    f32x4 oacc[2][4] = {};
    float mst[2] = {-1e30f, -1e30f}, lst[2] = {0.0f, 0.0f};
    int cur = 0;

    // prologue: stage tile 0 (4 ops/thread in flight)
#pragma unroll
    for (int j = 0; j < 2; ++j) {
        int ci = j * 256 + tid;
        int r = ci >> 3, c = ci & 7;
        int cs = (c ^ (r & 7)) * 8;
        GLD16(Kb + (size_t)r * DKK + cs, &Ks[cur][(j * 256 + wid * 64) * 8]);
        GLD16(Vb + (size_t)r * SS  + cs, &Vs[cur][(j * 256 + wid * 64) * 8]);
    }

#pragma unroll 1
    for (int t = 0; t < nt; ++t) {
        const int kv0 = t * 64;
        // prefetch next KV tile into other buffer, then wait for CURRENT only
        if (t + 1 < nt) {
            const int kvn = kv0 + 64;
#pragma unroll
            for (int j = 0; j < 2; ++j) {
                int ci = j * 256 + tid;
                int r = ci >> 3, c = ci & 7;
                int cs = (c ^ (r & 7)) * 8;
                GLD16(Kb + (size_t)(kvn + r) * DKK + cs, &Ks[cur ^ 1][(j * 256 + wid * 64) * 8]);
                GLD16(Vb + (size_t)r * SS + kvn + cs,    &Vs[cur ^ 1][(j * 256 + wid * 64) * 8]);
            }
            VMCNT(4);      // tile t's 4 done; tile t+1's 4 remain in flight
        } else {
            VMCNT(0);      // last tile: drain
        }
        bar();             // all waves see buf[cur] complete

        if (kv0 <= qw + 31) {   // wave has at least one unmasked column
            // ---- swapped QK^T: sacc[mi][ni] = S^T chunks ----
            f32x4 sacc[2][4] = {};
#pragma unroll
            for (int kk = 0; kk < 2; ++kk)
#pragma unroll
                for (int ni = 0; ni < 4; ++ni) {
                    int row = ni * 16 + lrow;
                    f16x8 kf = *(const f16x8*)&Ks[cur][row * 64 + ((kk * 4 + lk) ^ (row & 7)) * 8];
#pragma unroll
                    for (int mi = 0; mi < 2; ++mi)
                        sacc[mi][ni] = __builtin_amdgcn_mfma_f32_16x16x32_f16(
                            kf, qf[mi][kk], sacc[mi][ni], 0, 0, 0);
                }

            // ---- softmax: lane owns q = qw + mi*16 + lrow ----
#pragma unroll
            for (int mi = 0; mi < 2; ++mi) {
                const int q  = qw + mi * 16 + lrow;
                const int ql = mi * 16 + lrow;
                if (kv0 + 63 > q) {          // causal mask (diag tiles only)
#pragma unroll
                    for (int ni = 0; ni < 4; ++ni)
#pragma unroll
                        for (int r = 0; r < 4; ++r)
                            if (kv0 + ni * 16 + lk * 4 + r > q) sacc[mi][ni][r] = -1e30f;
                }
                float m0 = -1e30f;
#pragma unroll
                for (int ni = 0; ni < 4; ++ni) {
                    float a = fmaxf(sacc[mi][ni][0], sacc[mi][ni][1]);
                    float bx2 = fmaxf(sacc[mi][ni][2], sacc[mi][ni][3]);
                    m0 = fmaxf(m0, fmaxf(a, bx2));
                }
                m0 = fmaxf(m0, __shfl_xor(m0, 16));
                m0 = fmaxf(m0, __shfl_xor(m0, 32));
                // T13 defer-max: only rescale when the max really grew
                if (!__all(m0 - mst[mi] <= 11.5f)) {
                    const float mnew  = fmaxf(mst[mi], m0);
                    const float alpha = exp2f(mst[mi] - mnew);
                    mst[mi] = mnew;
                    lst[mi] *= alpha;
#pragma unroll
                    for (int no = 0; no < 4; ++no)
#pragma unroll
                        for (int r = 0; r < 4; ++r)
                            oacc[mi][no][r] *= alpha;
                }
                const float mref = mst[mi];
                float rsum = 0.0f;
#pragma unroll
                for (int ni = 0; ni < 4; ++ni) {
                    float p0 = exp2f(sacc[mi][ni][0] - mref);
                    float p1 = exp2f(sacc[mi][ni][1] - mref);
                    float p2 = exp2f(sacc[mi][ni][2] - mref);
                    float p3 = exp2f(sacc[mi][ni][3] - mref);
                    rsum += (p0 + p1) + (p2 + p3);
                    h16x2 w0 = __builtin_amdgcn_cvt_pkrtz(p0, p1);
                    h16x2 w1 = __builtin_amdgcn_cvt_pkrtz(p2, p3);
                    f16x4 w;
                    w[0] = (f16)w0[0]; w[1] = (f16)w0[1];
                    w[2] = (f16)w1[0]; w[3] = (f16)w1[1];
                    const int c = ni * 2 + (lk >> 1);
                    *(f16x4*)&PsW[ql * 64 + ((c ^ (ql & 7)) * 8) + (lk & 1) * 4] = w;
                }
                rsum += __shfl_xor(rsum, 16);
                rsum += __shfl_xor(rsum, 32);
                lst[mi] += rsum;
            }

            // ---- PV: O^T[dk][q] += V^T[dk][kv] x P[q][kv] ----
#pragma unroll
            for (int kk = 0; kk < 2; ++kk) {
                f16x8 pa[2];
#pragma unroll
                for (int mi = 0; mi < 2; ++mi) {
                    const int ql = mi * 16 + lrow;
                    pa[mi] = *(const f16x8*)&PsW[ql * 64 + ((kk * 4 + lk) ^ (ql & 7)) * 8];
                }
#pragma unroll
                for (int no = 0; no < 4; ++no) {
                    int row = no * 16 + lrow;
                    f16x8 vf = *(const f16x8*)&Vs[cur][row * 64 + ((kk * 4 + lk) ^ (row & 7)) * 8];
#pragma unroll
                    for (int mi = 0; mi < 2; ++mi)
                        oacc[mi][no] = __builtin_amdgcn_mfma_f32_16x16x32_f16(
                            vf, pa[mi], oacc[mi][no], 0, 0, 0);
                }
            }
        }

        bar();             // everyone done reading buf[cur] before it's re-staged
        cur ^= 1;
    }

    // normalize + store attn[b,s,h,dk] (f16); oacc[mi][no][r] = O[dk][q]
#pragma unroll
    for (int mi = 0; mi < 2; ++mi) {
        const float rl = 1.0f / lst[mi];
        const int q = qw + mi * 16 + lrow;
#pragma unroll
        for (int no = 0; no < 4; ++no) {
            f16x4 w;
#pragma unroll
            for (int r = 0; r < 4; ++r) w[r] = (f16)(oacc[mi][no][r] * rl);
            *(f16x4*)&attnB[((size_t)(b * SS) + q) * DD + h * DKK + no * 16 + lk * 4] = w;
        }
    }
}

// ---------------- Out projection GEMM (f32 output) ----------------
__global__ __launch_bounds__(256) void out_gemm(
    const f16* __restrict__ attnB, const f16* __restrict__ wob, float* __restrict__ out)
{
    __shared__ __align__(16) f16 As[2 * 128 * 64];
    __shared__ __align__(16) f16 Bs[2 * 128 * 64];
    const int bm = blockIdx.y * 128, bn = blockIdx.x * 128;
    f32x4 acc[4][4] = {};
    gemm_core(attnB, wob, As, Bs, acc, bm, bn);
    const int tid = threadIdx.x, lane = tid & 63, wid = tid >> 6;
    const int lrow = lane & 15, lk = lane >> 4;
    const int wm = (wid >> 1) * 64, wn = (wid & 1) * 64;
#pragma unroll
    for (int mi = 0; mi < 4; ++mi)
#pragma unroll
        for (int ni = 0; ni < 4; ++ni)
#pragma unroll
            for (int r = 0; r < 4; ++r) {
                int row = bm + wm + mi * 16 + lk * 4 + r;
                int col = bn + wn + ni * 16 + lrow;
                out[(size_t)row * 1024 + col] = acc[mi][ni][r];
            }
}

// ---------------------------------------------------------------------------
extern "C" void kernel_launch(void* const* d_in, const int* in_sizes, int n_in,
                              void* d_out, int out_size, void* d_ws, size_t ws_size,
                              hipStream_t stream) {
    const float* x  = (const float*)d_in[0];
    const float* wq = (const float*)d_in[1];
    const float* wk = (const float*)d_in[2];
    const float* wv = (const float*)d_in[3];
    const float* wo = (const float*)d_in[4];
    float* out = (float*)d_out;

    // workspace layout (f16 elements); attnB aliases xb (xb dead after QKV gemm)
    constexpr size_t NXB = (size_t)MM * DD;   // 8388608
    constexpr size_t NW  = (size_t)DD * DD;   // 1048576
    f16* xb  = (f16*)d_ws;
    f16* wqb = xb  + NXB;
    f16* wkb = wqb + NW;
    f16* wvb = wkb + NW;
    f16* wob = wvb + NW;
    f16* Qr  = wob + NW;
    f16* Kr  = Qr  + NXB;
    f16* Vt  = Kr  + NXB;
    float* ctab = (float*)(Vt + NXB);
    float* stab = ctab + SS * DKK;
    f16* attnB = xb;

    cvt_kernel<<<2048, 256, 0, stream>>>((const float4*)x, (f16x4*)xb, (int)(NXB / 4));
    cvt4_kernel<<<dim3(512, 4), 256, 0, stream>>>((const float4*)wq, (const float4*)wk,
                                                  (const float4*)wv, (const float4*)wo,
                                                  (f16x4*)wqb, (int)(NW / 4));
    rope_tab_kernel<<<(SS * DKK + 255) / 256, 256, 0, stream>>>(ctab, stab);

    qkv_gemm<<<dim3(8, 64, 3), 256, 0, stream>>>(xb, wqb, wkb, wvb, Qr, Kr, Vt, ctab, stab);
    attn_kernel<<<1024, 256, 0, stream>>>(Qr, Kr, Vt, attnB);
    out_gemm<<<dim3(8, 64), 256, 0, stream>>>(attnB, wob, out);
}

// Round 8
// 175.874 us; speedup vs baseline: 1.4757x; 1.0838x over previous
//
#include <hip/hip_runtime.h>

// ---------------------------------------------------------------------------
// MultiHeadSelfAttention: B=4 S=2048 D=1024 H=16 DK=64, RoPE, causal, out-proj
// Round 8: XCD-locality dispatch remapping (T1, 2D-aware) everywhere:
//   - qkv fused to ONE GEMM (N=3072), grid 1536: each XCD gets 8 A-rows x 24
//     col-blocks, y-fastest -> A(2MB)+B-panel resident in its L2
//   - out_gemm same mapping; attn groups 8 heads/XCD (K/V 4MB L2-resident)
//   GEMM/attn inner loops unchanged from round 7 (counted vmcnt pipeline).
// ---------------------------------------------------------------------------

typedef _Float16 f16;
typedef _Float16 f16x4 __attribute__((ext_vector_type(4)));
typedef _Float16 f16x8 __attribute__((ext_vector_type(8)));
typedef float    f32x4 __attribute__((ext_vector_type(4)));
typedef __fp16   h16x2 __attribute__((ext_vector_type(2)));

typedef __attribute__((address_space(1))) void gvoid_t;
typedef __attribute__((address_space(3))) void lvoid_t;

// async global->LDS, 16B per lane; LDS dest = wave-uniform base + lane*16
#define GLD16(g, l) __builtin_amdgcn_global_load_lds( \
    (gvoid_t*)(const void*)(g), (lvoid_t*)(l), 16, 0, 0)

// counted vmem wait: allow N instructions to remain in flight
#define VMCNT(n) asm volatile("s_waitcnt vmcnt(" #n ")" ::: "memory")

// raw workgroup barrier with scheduler fences (no vmcnt drain!)
__device__ __forceinline__ void bar() {
    __builtin_amdgcn_sched_barrier(0);
    __builtin_amdgcn_s_barrier();
    __builtin_amdgcn_sched_barrier(0);
}

constexpr int BB = 4, SS = 2048, DD = 1024, HH = 16, DKK = 64;
constexpr int MM = BB * SS;  // 8192

// ---------------- f32 -> f16 convert (vectorized) ----------------
__global__ void cvt_kernel(const float4* __restrict__ in, f16x4* __restrict__ out, int n4) {
    int stride = gridDim.x * blockDim.x;
    for (int i = blockIdx.x * blockDim.x + threadIdx.x; i < n4; i += stride) {
        float4 v = in[i];
        f16x4 o;
        o[0] = (f16)v.x; o[1] = (f16)v.y; o[2] = (f16)v.z; o[3] = (f16)v.w;
        out[i] = o;
    }
}

// 4 weight matrices in one launch; dst regions are contiguous in ws
__global__ void cvt4_kernel(const float4* __restrict__ a, const float4* __restrict__ b,
                            const float4* __restrict__ c, const float4* __restrict__ d,
                            f16x4* __restrict__ out, int n4per) {
    const float4* srcs[4] = {a, b, c, d};
    const float4* src = srcs[blockIdx.y];
    f16x4* dst = out + (size_t)blockIdx.y * n4per;
    int stride = gridDim.x * blockDim.x;
    for (int i = blockIdx.x * blockDim.x + threadIdx.x; i < n4per; i += stride) {
        float4 v = src[i];
        f16x4 o;
        o[0] = (f16)v.x; o[1] = (f16)v.y; o[2] = (f16)v.z; o[3] = (f16)v.w;
        dst[i] = o;
    }
}

// ---------------- RoPE tables: ctab/stab[s][dk] = cos/sin(s * invfreq[dk>>1])
__global__ void rope_tab_kernel(float* __restrict__ ctab, float* __restrict__ stab) {
    int idx = blockIdx.x * blockDim.x + threadIdx.x;
    if (idx >= SS * DKK) return;
    int s = idx >> 6, dk = idx & 63, i = dk >> 1;
    float inv = powf(10000.0f, -(float)(2 * i) / (float)DKK);
    float ang = (float)s * inv;
    ctab[idx] = cosf(ang);
    stab[idx] = sinf(ang);
}

// ---------------- GEMM core: C[128x128] tile, A[M][K], B-as-[N][K], K=1024 ---
// BK=64, double-buffered LDS, global_load_lds staging with XOR-swizzled source,
// counted vmcnt(8) pipeline: tile t+1's 8 loads/thread stay in flight across
// both barriers and the whole compute of tile t.
__device__ __forceinline__ void gemm_core(
    const f16* __restrict__ A, const f16* __restrict__ Bm,
    f16* As, f16* Bs, f32x4 (&acc)[4][4], int bm, int bn)
{
    const int tid  = threadIdx.x;
    const int lane = tid & 63, wid = tid >> 6;
    const int lrow = lane & 15, lk = lane >> 4;
    const int wm = (wid >> 1) * 64, wn = (wid & 1) * 64;

    const int r_ = tid >> 3, c_ = tid & 7;

    auto STAGE = [&](int buf, int k0) {
#pragma unroll
        for (int j = 0; j < 4; ++j) {
            int r = j * 32 + r_;
            int cs = (c_ ^ (r & 7)) * 8;
            GLD16(A  + (size_t)(bm + r) * 1024 + k0 + cs, As + buf * 8192 + (j * 256 + wid * 64) * 8);
            GLD16(Bm + (size_t)(bn + r) * 1024 + k0 + cs, Bs + buf * 8192 + (j * 256 + wid * 64) * 8);
        }
    };

    auto COMPUTE = [&](int buf) {
        const f16* Ab = As + buf * 8192;
        const f16* Bb = Bs + buf * 8192;
#pragma unroll
        for (int kk = 0; kk < 2; ++kk) {
            f16x8 af[4], bf[4];
#pragma unroll
            for (int mi = 0; mi < 4; ++mi) {
                int row = wm + mi * 16 + lrow;
                af[mi] = *(const f16x8*)&Ab[row * 64 + ((kk * 4 + lk) ^ (row & 7)) * 8];
            }
#pragma unroll
            for (int ni = 0; ni < 4; ++ni) {
                int row = wn + ni * 16 + lrow;
                bf[ni] = *(const f16x8*)&Bb[row * 64 + ((kk * 4 + lk) ^ (row & 7)) * 8];
            }
#pragma unroll
            for (int mi = 0; mi < 4; ++mi)
#pragma unroll
                for (int ni = 0; ni < 4; ++ni)
                    acc[mi][ni] = __builtin_amdgcn_mfma_f32_16x16x32_f16(
                        af[mi], bf[ni], acc[mi][ni], 0, 0, 0);
        }
    };

    STAGE(0, 0);           // tile 0 in flight (8 ops/thread)
    int cur = 0;
#pragma unroll 1
    for (int t = 0; t < 16; ++t) {
        if (t < 15) { STAGE(cur ^ 1, (t + 1) * 64); VMCNT(8); }  // wait tile t only
        else        { VMCNT(0); }                                 // last: drain
        bar();             // all waves see buf[cur] complete
        COMPUTE(cur);
        bar();             // everyone done reading buf[cur] before it's re-staged
        cur ^= 1;
    }
}

// ---------------- Fused QKV GEMM + RoPE epilogue ----------------
// One dispatch: M=8192, N=3072 (wq|wk|wv concatenated). Grid 1536 1D with
// XCD-locality mapping: x=i/64 (col-block), y=(i%8)*8+(i/8)%8 (row-block).
// Each XCD: 8 A-row-slabs (2MB, resident) x 24 col-blocks, y-fastest ->
// B-panel read once per XCD, A stays in L2.
__global__ __launch_bounds__(256) void qkv_gemm(
    const f16* __restrict__ xb, const f16* __restrict__ wqkv,
    f16* __restrict__ Qr, f16* __restrict__ Kr, f16* __restrict__ Vt,
    const float* __restrict__ ctab, const float* __restrict__ stab)
{
    __shared__ __align__(16) f16 As[2 * 128 * 64];
    __shared__ __align__(16) f16 Bs[2 * 128 * 64];
    const int i = blockIdx.x;
    const int xcol = i >> 6;                          // 0..23
    const int yrow = (i & 7) * 8 + ((i >> 3) & 7);    // 0..63
    const int bm = yrow * 128, bn = xcol * 128;
    const int z = bn >> 10;                            // 0=Q 1=K 2=V (uniform)
    const int bnw = bn & 1023;                         // col within its matrix

    f32x4 acc[4][4] = {};
    gemm_core(xb, wqkv, As, Bs, acc, bm, bn);

    const int tid = threadIdx.x, lane = tid & 63, wid = tid >> 6;
    const int lrow = lane & 15, lk = lane >> 4;
    const int wm = (wid >> 1) * 64, wn = (wid & 1) * 64;

    if (z == 2) {
        // V stored transposed: [b,h,dk,s] so attention stages Vt rows directly
#pragma unroll
        for (int mi = 0; mi < 4; ++mi)
#pragma unroll
            for (int ni = 0; ni < 4; ++ni)
#pragma unroll
                for (int r = 0; r < 4; ++r) {
                    int row = bm + wm + mi * 16 + lk * 4 + r;   // (b,s)
                    int col = bnw + wn + ni * 16 + lrow;         // (h,dk)
                    int b = row >> 11, s = row & 2047, h = col >> 6, dk = col & 63;
                    Vt[((size_t)(b * HH + h) * DKK + dk) * SS + s] = (f16)acc[mi][ni][r];
                }
    } else {
        f16* Out = (z == 0) ? Qr : Kr;
        // fold 1/sqrt(DK) AND log2e (attn works in exp2 domain) into Q
        const float scale = (z == 0) ? 0.125f * 1.44269504088896f : 1.0f;
#pragma unroll
        for (int mi = 0; mi < 4; ++mi)
#pragma unroll
            for (int ni = 0; ni < 4; ++ni)
#pragma unroll
                for (int r = 0; r < 4; ++r) {
                    int row = bm + wm + mi * 16 + lk * 4 + r;
                    int col = bnw + wn + ni * 16 + lrow;
                    int b = row >> 11, s = row & 2047, h = col >> 6, dk = col & 63;
                    float v = acc[mi][ni][r];
                    float partner = __shfl_xor(v, 1);   // adjacent column (same rows)
                    float cc = ctab[s * DKK + dk], ssn = stab[s * DKK + dk];
                    float rot = (col & 1) ? partner : -partner;
                    float o = (v * cc + rot * ssn) * scale;
                    Out[((size_t)(b * HH + h) * SS + s) * DKK + dk] = (f16)o;
                }
    }
}

// ---------------- Flash attention ----------------
// 1024 blocks 1D. XCD-locality: bh=(i%8)*8+(i/8)%8, qt=15-(i/64) ->
// each XCD owns 8 heads (K+V = 4MB, L2-resident), heavy q-tiles dispatch
// first within each XCD. 4 waves; wave owns 32 q-rows. Swapped QK^T,
// lane-local softmax, exp2 domain, T13 defer-max, counted vmcnt(4).
__global__ __launch_bounds__(256, 3) void attn_kernel(
    const f16* __restrict__ Q, const f16* __restrict__ K, const f16* __restrict__ Vt,
    f16* __restrict__ attnB)
{
    __shared__ __align__(16) f16 Ks[2][64 * 64];   // [kv][dk], swizzled chunks
    __shared__ __align__(16) f16 Vs[2][64 * 64];   // [dk][kv], swizzled chunks
    __shared__ __align__(16) f16 Ps[4][32 * 64];   // per-wave P[q_local][kv], swizzled

    const int tid = threadIdx.x, lane = tid & 63, wid = tid >> 6;
    const int lrow = lane & 15, lk = lane >> 4;
    const int bx = blockIdx.x;
    const int qt = 15 - (bx >> 6);                   // heavy-first per XCD
    const int bh = (bx & 7) * 8 + ((bx >> 3) & 7);   // 8 heads per XCD
    const int b = bh >> 4, h = bh & 15;

    const f16* Qb = Q  + (size_t)bh * SS * DKK;
    const f16* Kb = K  + (size_t)bh * SS * DKK;
    const f16* Vb = Vt + (size_t)bh * DKK * SS;
    f16* PsW = &Ps[wid][0];

    const int qw = qt * 128 + wid * 32;      // this wave's 32 q-rows
    const int nt = 2 * qt + 2;               // causal KV tiles of 64

    // Q fragments in registers: qf[mi][kk] = Q[qw+mi*16+lrow][kk*32+lk*8..]
    f16x8 qf[2][2];
#pragma unroll
    for (int mi = 0; mi < 2; ++mi)
#pragma unroll
        for (int kk = 0; kk < 2; ++kk)
            qf[mi][kk] = *(const f16x8*)&Qb[(size_t)(qw + mi * 16 + lrow) * DKK + kk * 32 + lk * 8];

    f32x4 oacc[2][4] = {};
    float mst[2] = {-1e30f, -1e30f}, lst[2] = {0.0f, 0.0f};
    int cur = 0;

    // prologue: stage tile 0 (4 ops/thread in flight)
#pragma unroll
    for (int j = 0; j < 2; ++j) {
        int ci = j * 256 + tid;
        int r = ci >> 3, c = ci & 7;
        int cs = (c ^ (r & 7)) * 8;
        GLD16(Kb + (size_t)r * DKK + cs, &Ks[cur][(j * 256 + wid * 64) * 8]);
        GLD16(Vb + (size_t)r * SS  + cs, &Vs[cur][(j * 256 + wid * 64) * 8]);
    }

#pragma unroll 1
    for (int t = 0; t < nt; ++t) {
        const int kv0 = t * 64;
        // prefetch next KV tile into other buffer, then wait for CURRENT only
        if (t + 1 < nt) {
            const int kvn = kv0 + 64;
#pragma unroll
            for (int j = 0; j < 2; ++j) {
                int ci = j * 256 + tid;
                int r = ci >> 3, c = ci & 7;
                int cs = (c ^ (r & 7)) * 8;
                GLD16(Kb + (size_t)(kvn + r) * DKK + cs, &Ks[cur ^ 1][(j * 256 + wid * 64) * 8]);
                GLD16(Vb + (size_t)r * SS + kvn + cs,    &Vs[cur ^ 1][(j * 256 + wid * 64) * 8]);
            }
            VMCNT(4);      // tile t's 4 done; tile t+1's 4 remain in flight
        } else {
            VMCNT(0);      // last tile: drain
        }
        bar();             // all waves see buf[cur] complete

        if (kv0 <= qw + 31) {   // wave has at least one unmasked column
            // ---- swapped QK^T: sacc[mi][ni] = S^T chunks ----
            f32x4 sacc[2][4] = {};
#pragma unroll
            for (int kk = 0; kk < 2; ++kk)
#pragma unroll
                for (int ni = 0; ni < 4; ++ni) {
                    int row = ni * 16 + lrow;
                    f16x8 kf = *(const f16x8*)&Ks[cur][row * 64 + ((kk * 4 + lk) ^ (row & 7)) * 8];
#pragma unroll
                    for (int mi = 0; mi < 2; ++mi)
                        sacc[mi][ni] = __builtin_amdgcn_mfma_f32_16x16x32_f16(
                            kf, qf[mi][kk], sacc[mi][ni], 0, 0, 0);
                }

            // ---- softmax: lane owns q = qw + mi*16 + lrow ----
#pragma unroll
            for (int mi = 0; mi < 2; ++mi) {
                const int q  = qw + mi * 16 + lrow;
                const int ql = mi * 16 + lrow;
                if (kv0 + 63 > q) {          // causal mask (diag tiles only)
#pragma unroll
                    for (int ni = 0; ni < 4; ++ni)
#pragma unroll
                        for (int r = 0; r < 4; ++r)
                            if (kv0 + ni * 16 + lk * 4 + r > q) sacc[mi][ni][r] = -1e30f;
                }
                float m0 = -1e30f;
#pragma unroll
                for (int ni = 0; ni < 4; ++ni) {
                    float a = fmaxf(sacc[mi][ni][0], sacc[mi][ni][1]);
                    float bx2 = fmaxf(sacc[mi][ni][2], sacc[mi][ni][3]);
                    m0 = fmaxf(m0, fmaxf(a, bx2));
                }
                m0 = fmaxf(m0, __shfl_xor(m0, 16));
                m0 = fmaxf(m0, __shfl_xor(m0, 32));
                // T13 defer-max: only rescale when the max really grew
                if (!__all(m0 - mst[mi] <= 11.5f)) {
                    const float mnew  = fmaxf(mst[mi], m0);
                    const float alpha = exp2f(mst[mi] - mnew);
                    mst[mi] = mnew;
                    lst[mi] *= alpha;
#pragma unroll
                    for (int no = 0; no < 4; ++no)
#pragma unroll
                        for (int r = 0; r < 4; ++r)
                            oacc[mi][no][r] *= alpha;
                }
                const float mref = mst[mi];
                float rsum = 0.0f;
#pragma unroll
                for (int ni = 0; ni < 4; ++ni) {
                    float p0 = exp2f(sacc[mi][ni][0] - mref);
                    float p1 = exp2f(sacc[mi][ni][1] - mref);
                    float p2 = exp2f(sacc[mi][ni][2] - mref);
                    float p3 = exp2f(sacc[mi][ni][3] - mref);
                    rsum += (p0 + p1) + (p2 + p3);
                    h16x2 w0 = __builtin_amdgcn_cvt_pkrtz(p0, p1);
                    h16x2 w1 = __builtin_amdgcn_cvt_pkrtz(p2, p3);
                    f16x4 w;
                    w[0] = (f16)w0[0]; w[1] = (f16)w0[1];
                    w[2] = (f16)w1[0]; w[3] = (f16)w1[1];
                    const int c = ni * 2 + (lk >> 1);
                    *(f16x4*)&PsW[ql * 64 + ((c ^ (ql & 7)) * 8) + (lk & 1) * 4] = w;
                }
                rsum += __shfl_xor(rsum, 16);
                rsum += __shfl_xor(rsum, 32);
                lst[mi] += rsum;
            }

            // ---- PV: O^T[dk][q] += V^T[dk][kv] x P[q][kv] ----
#pragma unroll
            for (int kk = 0; kk < 2; ++kk) {
                f16x8 pa[2];
#pragma unroll
                for (int mi = 0; mi < 2; ++mi) {
                    const int ql = mi * 16 + lrow;
                    pa[mi] = *(const f16x8*)&PsW[ql * 64 + ((kk * 4 + lk) ^ (ql & 7)) * 8];
                }
#pragma unroll
                for (int no = 0; no < 4; ++no) {
                    int row = no * 16 + lrow;
                    f16x8 vf = *(const f16x8*)&Vs[cur][row * 64 + ((kk * 4 + lk) ^ (row & 7)) * 8];
#pragma unroll
                    for (int mi = 0; mi < 2; ++mi)
                        oacc[mi][no] = __builtin_amdgcn_mfma_f32_16x16x32_f16(
                            vf, pa[mi], oacc[mi][no], 0, 0, 0);
                }
            }
        }

        bar();             // everyone done reading buf[cur] before it's re-staged
        cur ^= 1;
    }

    // normalize + store attn[b,s,h,dk] (f16); oacc[mi][no][r] = O[dk][q]
#pragma unroll
    for (int mi = 0; mi < 2; ++mi) {
        const float rl = 1.0f / lst[mi];
        const int q = qw + mi * 16 + lrow;
#pragma unroll
        for (int no = 0; no < 4; ++no) {
            f16x4 w;
#pragma unroll
            for (int r = 0; r < 4; ++r) w[r] = (f16)(oacc[mi][no][r] * rl);
            *(f16x4*)&attnB[((size_t)(b * SS) + q) * DD + h * DKK + no * 16 + lk * 4] = w;
        }
    }
}

// ---------------- Out projection GEMM (f32 output) ----------------
// 512 blocks 1D, same XCD-locality mapping as qkv (x=i/64 in 0..7).
__global__ __launch_bounds__(256) void out_gemm(
    const f16* __restrict__ attnB, const f16* __restrict__ wob, float* __restrict__ out)
{
    __shared__ __align__(16) f16 As[2 * 128 * 64];
    __shared__ __align__(16) f16 Bs[2 * 128 * 64];
    const int i = blockIdx.x;
    const int xcol = i >> 6;                          // 0..7
    const int yrow = (i & 7) * 8 + ((i >> 3) & 7);    // 0..63
    const int bm = yrow * 128, bn = xcol * 128;
    f32x4 acc[4][4] = {};
    gemm_core(attnB, wob, As, Bs, acc, bm, bn);
    const int tid = threadIdx.x, lane = tid & 63, wid = tid >> 6;
    const int lrow = lane & 15, lk = lane >> 4;
    const int wm = (wid >> 1) * 64, wn = (wid & 1) * 64;
#pragma unroll
    for (int mi = 0; mi < 4; ++mi)
#pragma unroll
        for (int ni = 0; ni < 4; ++ni)
#pragma unroll
            for (int r = 0; r < 4; ++r) {
                int row = bm + wm + mi * 16 + lk * 4 + r;
                int col = bn + wn + ni * 16 + lrow;
                out[(size_t)row * 1024 + col] = acc[mi][ni][r];
            }
}

// ---------------------------------------------------------------------------
extern "C" void kernel_launch(void* const* d_in, const int* in_sizes, int n_in,
                              void* d_out, int out_size, void* d_ws, size_t ws_size,
                              hipStream_t stream) {
    const float* x  = (const float*)d_in[0];
    const float* wq = (const float*)d_in[1];
    const float* wk = (const float*)d_in[2];
    const float* wv = (const float*)d_in[3];
    const float* wo = (const float*)d_in[4];
    float* out = (float*)d_out;

    // workspace layout (f16 elements); attnB aliases xb (xb dead after QKV gemm)
    constexpr size_t NXB = (size_t)MM * DD;   // 8388608
    constexpr size_t NW  = (size_t)DD * DD;   // 1048576
    f16* xb  = (f16*)d_ws;
    f16* wqkv = xb + NXB;          // wq|wk|wv|wo contiguous (cvt4)
    f16* wob  = wqkv + 3 * NW;
    f16* Qr  = wob + NW;
    f16* Kr  = Qr  + NXB;
    f16* Vt  = Kr  + NXB;
    float* ctab = (float*)(Vt + NXB);
    float* stab = ctab + SS * DKK;
    f16* attnB = xb;

    cvt_kernel<<<2048, 256, 0, stream>>>((const float4*)x, (f16x4*)xb, (int)(NXB / 4));
    cvt4_kernel<<<dim3(512, 4), 256, 0, stream>>>((const float4*)wq, (const float4*)wk,
                                                  (const float4*)wv, (const float4*)wo,
                                                  (f16x4*)wqkv, (int)(NW / 4));
    rope_tab_kernel<<<(SS * DKK + 255) / 256, 256, 0, stream>>>(ctab, stab);

    qkv_gemm<<<1536, 256, 0, stream>>>(xb, wqkv, Qr, Kr, Vt, ctab, stab);
    attn_kernel<<<1024, 256, 0, stream>>>(Qr, Kr, Vt, attnB);
    out_gemm<<<512, 256, 0, stream>>>(attnB, wob, out);
}